// Round 1
// baseline (1002.012 us; speedup 1.0000x reference)
//
#include <hip/hip_runtime.h>
#include <math.h>

#define S_LEN 512
#define TCHUNK 64

__device__ __forceinline__ float fast_rcp(float x) { return __builtin_amdgcn_rcpf(x); }

__global__ __launch_bounds__(128) void prnn_kernel(
    const float* __restrict__ x,
    const float* __restrict__ W1,
    const float* __restrict__ W2,
    float* __restrict__ out)
{
    // Material constants, computed in double then truncated to f32 (matches JAX weak-typing)
    constexpr float MU    = (float)(3130.0 / (2.0 * 1.3));            // E/(2(1+nu))
    constexpr float LAM   = (float)(3130.0 * 0.3 / (1.3 * 0.4));      // E nu/((1+nu)(1-2nu))
    constexpr float AH    = 64.8f;
    constexpr float BH    = 33.6f;
    constexpr float INVC  = (float)(1.0 / 0.003407);
    const float TWO_MU    = 2.0f * MU;
    const float THREE_MU  = 3.0f * MU;
    const float BH_INVC   = BH * INVC;

    const int b    = blockIdx.x;
    const int tid  = threadIdx.x;   // material point index m in [0,128)
    const int lane = tid & 63;
    const int wv   = tid >> 6;

    // Per-thread weights in registers
    float w1[3][3];   // w1[j][f] = W1[(m*3+j), f]
    float w2[3][3];   // w2[o][j] = W2[o, m*3+j]
    #pragma unroll
    for (int j = 0; j < 3; ++j)
        #pragma unroll
        for (int f = 0; f < 3; ++f)
            w1[j][f] = W1[(tid * 3 + j) * 3 + f];
    #pragma unroll
    for (int o = 0; o < 3; ++o)
        #pragma unroll
        for (int j = 0; j < 3; ++j)
            w2[o][j] = W2[o * 384 + tid * 3 + j];

    __shared__ float xs[S_LEN * 3];         // 6 KB: full strain history of batch b
    __shared__ float part[2][TCHUNK * 3];   // 1.5 KB: per-wave partial outputs

    const float* xb = x + (size_t)b * (S_LEN * 3);
    for (int i = tid; i < S_LEN * 3; i += 128) xs[i] = xb[i];
    __syncthreads();

    float ep0 = 0.f, ep1 = 0.f, ep2 = 0.f, ep3 = 0.f, kap = 0.f;

    float* outb = out + (size_t)b * (S_LEN * 3);

    for (int tc = 0; tc < S_LEN; tc += TCHUNK) {
        #pragma unroll 1
        for (int tt = 0; tt < TCHUNK; ++tt) {
            const int t = tc + tt;
            const float x0 = xs[t * 3 + 0], x1 = xs[t * 3 + 1], x2 = xs[t * 3 + 2];

            // fc1: strain for this material point (exx, eyy, gxy engineering)
            const float e0 = w1[0][0] * x0 + w1[0][1] * x1 + w1[0][2] * x2;
            const float e1 = w1[1][0] * x0 + w1[1][1] * x1 + w1[1][2] * x2;
            const float g  = w1[2][0] * x0 + w1[2][1] * x1 + w1[2][2] * x2;

            // Elastic trial (tensorial Voigt-4: xx, yy, zz, xy)
            const float ee0 = e0 - ep0;
            const float ee1 = e1 - ep1;
            const float ee2 = -ep2;
            const float ee3 = 0.5f * g - ep3;
            const float lt  = LAM * (ee0 + ee1 + ee2);
            const float s0 = TWO_MU * ee0 + lt;
            const float s1 = TWO_MU * ee1 + lt;
            const float s2 = TWO_MU * ee2 + lt;
            const float s3 = TWO_MU * ee3;
            const float p  = (s0 + s1 + s2) * (1.0f / 3.0f);
            const float d0 = s0 - p, d1 = s1 - p, d2 = s2 - p, d3 = s3;
            const float q  = sqrtf(1.5f * (d0 * d0 + d1 * d1 + d2 * d2 + 2.0f * d3 * d3));
            const float sy = AH - BH * __expf(-kap * INVC);
            const float f  = q - sy;

            float dg = 0.0f;
            if (__any(f > 0.0f)) {
                // Newton return mapping; dg stays clamped at 0 for elastic lanes,
                // so the f<=0 select below matches the reference exactly.
                #pragma unroll 1
                for (int it = 0; it < 12; ++it) {
                    const float ex  = __expf(-(kap + dg) * INVC);
                    const float r   = q - THREE_MU * dg - AH + BH * ex;
                    const float dr  = -THREE_MU - BH_INVC * ex;
                    const float dgn = fmaxf(dg - r * fast_rcp(dr), 0.0f);
                    const bool conv = fabsf(dgn - dg) < 1e-7f;
                    dg = dgn;
                    if (__all(conv)) break;
                }
                dg = (f > 0.0f) ? dg : 0.0f;
            }

            // Radial return: dg*n = c*d with c = 1.5*dg/q_safe
            const float c  = 1.5f * dg * fast_rcp(fmaxf(q, 1e-12f));
            const float t2 = TWO_MU * c;
            const float r0 = s0 - t2 * d0;   // sxx
            const float r1 = s1 - t2 * d1;   // syy
            const float r3 = s3 - t2 * d3;   // sxy
            ep0 += c * d0; ep1 += c * d1; ep2 += c * d2; ep3 += c * d3;
            kap += dg;

            // fc2 partial: this point's contribution to out[b,t,0..2]
            float c0 = w2[0][0] * r0 + w2[0][1] * r1 + w2[0][2] * r3;
            float c1 = w2[1][0] * r0 + w2[1][1] * r1 + w2[1][2] * r3;
            float c2 = w2[2][0] * r0 + w2[2][1] * r1 + w2[2][2] * r3;

            // 64-lane butterfly reduce
            #pragma unroll
            for (int off = 32; off >= 1; off >>= 1) {
                c0 += __shfl_xor(c0, off, 64);
                c1 += __shfl_xor(c1, off, 64);
                c2 += __shfl_xor(c2, off, 64);
            }
            if (lane == 0) {
                part[wv][tt * 3 + 0] = c0;
                part[wv][tt * 3 + 1] = c1;
                part[wv][tt * 3 + 2] = c2;
            }
        }
        __syncthreads();
        // Combine the two waves and store 64 timesteps coalesced
        for (int i = tid; i < TCHUNK * 3; i += 128)
            outb[tc * 3 + i] = part[0][i] + part[1][i];
        __syncthreads();
    }
}

extern "C" void kernel_launch(void* const* d_in, const int* in_sizes, int n_in,
                              void* d_out, int out_size, void* d_ws, size_t ws_size,
                              hipStream_t stream) {
    const float* x  = (const float*)d_in[0];
    const float* W1 = (const float*)d_in[1];
    const float* W2 = (const float*)d_in[2];
    float* out = (float*)d_out;
    prnn_kernel<<<4096, 128, 0, stream>>>(x, W1, W2, out);
}

// Round 2
// 762.224 us; speedup vs baseline: 1.3146x; 1.3146x over previous
//
#include <hip/hip_runtime.h>
#include <math.h>

#define S_LEN 512
#define TCHUNK 16
#define PSTRIDE 99   // 3*33 dwords: part[tt][o*33 + g], g in [0,32)

__device__ __forceinline__ float fast_rcp(float x) { return __builtin_amdgcn_rcpf(x); }

__global__ __launch_bounds__(128) void prnn_kernel(
    const float* __restrict__ x,
    const float* __restrict__ W1,
    const float* __restrict__ W2,
    float* __restrict__ out)
{
    constexpr float MU    = (float)(3130.0 / (2.0 * 1.3));
    constexpr float AH    = 64.8f;
    constexpr float BH    = 33.6f;
    constexpr float INVC  = (float)(1.0 / 0.003407);
    constexpr float LAM   = (float)(3130.0 * 0.3 / (1.3 * 0.4));
    const float TWO_MU    = 2.0f * MU;
    const float THREE_MU  = 3.0f * MU;
    const float RCP3MU    = 1.0f / (3.0f * MU);
    const float BH_INVC   = BH * INVC;

    const int b    = blockIdx.x;
    const int tid  = threadIdx.x;       // material point m in [0,128)
    const int lane = tid & 63;
    const int wv   = tid >> 6;

    float w1[3][3], w2[3][3];
    #pragma unroll
    for (int j = 0; j < 3; ++j)
        #pragma unroll
        for (int f = 0; f < 3; ++f)
            w1[j][f] = W1[(tid * 3 + j) * 3 + f];
    #pragma unroll
    for (int o = 0; o < 3; ++o)
        #pragma unroll
        for (int j = 0; j < 3; ++j)
            w2[o][j] = W2[o * 384 + tid * 3 + j];

    __shared__ float xs[S_LEN * 3];            // 6 KB
    __shared__ float part[TCHUNK * PSTRIDE];   // 6.2 KB

    const float* xb = x + (size_t)b * (S_LEN * 3);
    for (int i = tid; i < S_LEN * 3; i += 128) xs[i] = xb[i];
    __syncthreads();

    float ep0 = 0.f, ep1 = 0.f, ep2 = 0.f, ep3 = 0.f, kap = 0.f;
    float* outb = out + (size_t)b * (S_LEN * 3);

    const int  g3  = wv * 16 + (lane >> 2);    // partial slot 0..31
    const bool wrt = (lane & 3) == 0;

    for (int tc = 0; tc < S_LEN; tc += TCHUNK) {
        #pragma unroll 1
        for (int tt = 0; tt < TCHUNK; ++tt) {
            const int t = tc + tt;
            const float x0 = xs[t * 3 + 0], x1 = xs[t * 3 + 1], x2 = xs[t * 3 + 2];

            // fc1
            const float e0 = w1[0][0] * x0 + w1[0][1] * x1 + w1[0][2] * x2;
            const float e1 = w1[1][0] * x0 + w1[1][1] * x1 + w1[1][2] * x2;
            const float g  = w1[2][0] * x0 + w1[2][1] * x1 + w1[2][2] * x2;

            // elastic trial (tensorial Voigt-4)
            const float ee0 = e0 - ep0;
            const float ee1 = e1 - ep1;
            const float ee2 = -ep2;
            const float ee3 = 0.5f * g - ep3;
            const float lt  = LAM * (ee0 + ee1 + ee2);
            const float s0 = TWO_MU * ee0 + lt;
            const float s1 = TWO_MU * ee1 + lt;
            const float s2 = TWO_MU * ee2 + lt;
            const float s3 = TWO_MU * ee3;
            const float p  = (s0 + s1 + s2) * (1.0f / 3.0f);
            const float d0 = s0 - p, d1 = s1 - p, d2 = s2 - p, d3 = s3;
            const float q  = sqrtf(1.5f * (d0 * d0 + d1 * d1 + d2 * d2 + 2.0f * d3 * d3));
            const float sy = AH - BH * __expf(-kap * INVC);
            const float f  = q - sy;

            float r0 = s0, r1 = s1, r3 = s3;   // elastic default

            if (__any(f > 0.0f)) {
                // Closed form + one Newton polish (valid when bex <= 2, i.e. kappa+dg >= ~0.01)
                const float dg_cf = fmaxf((q - AH) * RCP3MU, 0.0f);
                const float ex_u  = __expf(-(kap + dg_cf) * INVC);
                const float bex   = BH * ex_u;
                const float res   = q - THREE_MU * dg_cf - AH + bex;  // == bex (unclamped) or f (clamped)
                float dg = dg_cf + res * fast_rcp(THREE_MU + INVC * bex);
                dg = (f > 0.0f) ? dg : 0.0f;

                const bool slow = (f > 0.0f) && (bex > 2.0f);
                if (__any(slow)) {
                    // Newton from dg (left of root -> monotone convergent); elastic lanes stay 0
                    #pragma unroll 1
                    for (int it = 0; it < 12; ++it) {
                        const float ex  = __expf(-(kap + dg) * INVC);
                        const float r   = q - THREE_MU * dg - AH + BH * ex;
                        const float dr  = -THREE_MU - BH_INVC * ex;
                        const float dgn = fmaxf(dg - r * fast_rcp(dr), 0.0f);
                        const bool conv = fabsf(dgn - dg) < 1e-7f;
                        dg = dgn;
                        if (__all(conv)) break;
                    }
                    dg = (f > 0.0f) ? dg : 0.0f;
                }

                // radial return + state update (no-op for dg==0 lanes)
                const float c  = 1.5f * dg * fast_rcp(fmaxf(q, 1e-12f));
                const float t2 = TWO_MU * c;
                r0 = s0 - t2 * d0;
                r1 = s1 - t2 * d1;
                r3 = s3 - t2 * d3;
                ep0 += c * d0; ep1 += c * d1; ep2 += c * d2; ep3 += c * d3;
                kap += dg;
            }

            // fc2 contribution
            float c0 = w2[0][0] * r0 + w2[0][1] * r1 + w2[0][2] * r3;
            float c1 = w2[1][0] * r0 + w2[1][1] * r1 + w2[1][2] * r3;
            float c2 = w2[2][0] * r0 + w2[2][1] * r1 + w2[2][2] * r3;

            // 4-lane pre-reduce (2 shuffle levels)
            c0 += __shfl_xor(c0, 1, 64); c0 += __shfl_xor(c0, 2, 64);
            c1 += __shfl_xor(c1, 1, 64); c1 += __shfl_xor(c1, 2, 64);
            c2 += __shfl_xor(c2, 1, 64); c2 += __shfl_xor(c2, 2, 64);
            if (wrt) {
                float* pp = &part[tt * PSTRIDE + g3];
                pp[0]  = c0;   // o=0
                pp[33] = c1;   // o=1
                pp[66] = c2;   // o=2
            }
        }
        __syncthreads();
        // finish reduction: thread i<48 handles (tt=i/3, o=i%3); store coalesced
        if (tid < 48) {
            const int rtt = tid / 3, ro = tid - rtt * 3;
            const float* pp = &part[rtt * PSTRIDE + ro * 33];
            float s = 0.0f;
            #pragma unroll
            for (int gg = 0; gg < 32; ++gg) s += pp[gg];
            outb[tc * 3 + tid] = s;
        }
        __syncthreads();
    }
}

extern "C" void kernel_launch(void* const* d_in, const int* in_sizes, int n_in,
                              void* d_out, int out_size, void* d_ws, size_t ws_size,
                              hipStream_t stream) {
    const float* x  = (const float*)d_in[0];
    const float* W1 = (const float*)d_in[1];
    const float* W2 = (const float*)d_in[2];
    float* out = (float*)d_out;
    prnn_kernel<<<4096, 128, 0, stream>>>(x, W1, W2, out);
}

// Round 3
// 731.119 us; speedup vs baseline: 1.3705x; 1.0425x over previous
//
#include <hip/hip_runtime.h>
#include <math.h>

#define S_LEN 512
#define TCHUNK 16
#define PSTRIDE 99   // 3*33 dwords: part[tt][o*33 + g], g in [0,32)

typedef float v2f __attribute__((ext_vector_type(2)));

__device__ __forceinline__ float fast_rcp(float x) { return __builtin_amdgcn_rcpf(x); }
__device__ __forceinline__ float fast_rsq(float x) { return __builtin_amdgcn_rsqf(x); }
__device__ __forceinline__ float exp2f_(float x)   { return __builtin_amdgcn_exp2f(x); }

__global__ __launch_bounds__(128) void prnn_kernel(
    const float* __restrict__ x,
    const float* __restrict__ W1,
    const float* __restrict__ W2,
    float* __restrict__ out)
{
    // Material constants (double-precision compile-time, truncated to f32)
    const float TWO_MU  = (float)(2.0 * (3130.0 / 2.6));            // 2*MU
    const float LAM     = (float)(3130.0 * 0.3 / (1.3 * 0.4));
    const float AH = 64.8f, BH = 33.6f;
    const float Cf      = 0.003407f;
    const float K2      = (float)(1.4426950408889634 / 0.003407);   // log2(e)/C
    const float RCP3MU  = (float)(1.0 / (3.0 * (3130.0 / 2.6)));
    const float L2B3MC  = 1.4492834f;                               // log2(B/(3*MU*C)), 3*MU*C=12.3045115
    const float LN2     = 0.6931471805599453f;
    const float LOG2E   = 1.4426950408889634f;

    const int b    = blockIdx.x;
    const int tid  = threadIdx.x;      // material point m in [0,128)
    const int lane = tid & 63;
    const int wv   = tid >> 6;

    // fc1 weights: rows (0,1) packed as v2f, row 2 scalar
    v2f w1p[3]; float w1r2[3];
    #pragma unroll
    for (int f = 0; f < 3; ++f) {
        w1p[f]  = (v2f){ W1[(tid*3+0)*3 + f], W1[(tid*3+1)*3 + f] };
        w1r2[f] = W1[(tid*3+2)*3 + f];
    }
    // fc2 weights: outputs (0,1) packed, output 2 scalar
    v2f w2p[3]; float w2r2[3];
    #pragma unroll
    for (int j = 0; j < 3; ++j) {
        w2p[j]  = (v2f){ W2[0*384 + tid*3 + j], W2[1*384 + tid*3 + j] };
        w2r2[j] = W2[2*384 + tid*3 + j];
    }

    __shared__ float xs[S_LEN*3];
    __shared__ float part[TCHUNK*PSTRIDE];

    const float* xb = x + (size_t)b*(S_LEN*3);
    for (int i = tid; i < S_LEN*3; i += 128) xs[i] = xb[i];
    __syncthreads();

    v2f ep01 = {0.f, 0.f}, ep23 = {0.f, 0.f};
    float kap = 0.f;
    float* outb = out + (size_t)b*(S_LEN*3);

    const int  g3  = wv*16 + (lane >> 2);
    const bool wrt = (lane & 3) == 0;

    for (int tc = 0; tc < S_LEN; tc += TCHUNK) {
        #pragma unroll 1
        for (int tt = 0; tt < TCHUNK; ++tt) {
            const int t = tc + tt;
            const float x0 = xs[t*3+0], x1 = xs[t*3+1], x2 = xs[t*3+2];

            // fc1 (x* are wave-uniform broadcasts)
            v2f   e01 = w1p[0]*x0 + w1p[1]*x1 + w1p[2]*x2;
            float g   = w1r2[0]*x0 + w1r2[1]*x1 + w1r2[2]*x2;

            // elastic trial (tensorial Voigt-4: xx,yy | zz,xy)
            v2f ee01 = e01 - ep01;
            v2f ee23 = (v2f){0.f, 0.5f*g} - ep23;
            const float lt = LAM * (ee01.x + ee01.y + ee23.x);
            v2f s01 = TWO_MU*ee01 + (v2f){lt, lt};
            v2f s23 = TWO_MU*ee23 + (v2f){lt, 0.f};
            const float p = (s01.x + s01.y + s23.x) * (1.0f/3.0f);
            v2f d01 = s01 - (v2f){p, p};
            v2f d23 = s23 - (v2f){p, 0.f};
            v2f m1 = d01*d01;
            v2f m2 = d23*d23;
            const float dot15 = fmaxf(1.5f*(m1.x + m1.y + m2.x + 2.0f*m2.y), 1e-24f);
            const float qi = fast_rsq(dot15);      // 1/q
            const float q  = dot15 * qi;
            const float E  = exp2f_(-kap * K2);    // e^{-kappa/C}
            const float f  = q - AH + BH*E;        // yield function

            v2f rs01 = s01; float rs3 = s23.y;     // elastic default

            if (__any(f > 0.0f)) {
                // Lambert-W closed form: dg = u0 + C*W(z), z = (B/(3muC)) e^{-(kap+u0)/C}
                const float u0  = (q - AH) * RCP3MU;
                const float l2z = __builtin_fmaf(-(kap + u0), K2, L2B3MC);  // log2(z)
                const float z   = exp2f_(l2z);
                const float lnz = l2z * LN2;
                float w = fmaxf(0.8f*lnz, z*fast_rcp(1.0f + z));   // branchless init
                #pragma unroll
                for (int hh = 0; hh < 2; ++hh) {                   // 2 Halley steps (cubic)
                    const float y   = exp2f_(w * LOG2E);           // e^w
                    const float F   = __builtin_fmaf(w, y, -z);    // w e^w - z
                    const float Fp  = __builtin_fmaf(w, y, y);     // y(1+w)
                    const float Fpp = F * y * (2.0f + w);          // F * F''
                    const float den = __builtin_fmaf(Fp, Fp, -0.5f*Fpp);
                    w = __builtin_fmaf(-F*Fp, fast_rcp(den), w);
                }
                float dg = __builtin_fmaf(w, Cf, u0);
                dg = (f > 0.0f) ? fmaxf(dg, 0.0f) : 0.0f;

                // radial return + state update (exact no-op for dg==0 lanes)
                const float c  = 1.5f * dg * qi;
                const float t2 = TWO_MU * c;
                rs01 = s01 - t2*d01;
                rs3  = __builtin_fmaf(-t2, d23.y, s23.y);
                ep01 = ep01 + c*d01;
                ep23 = ep23 + c*d23;
                kap += dg;
            }

            // fc2 contribution
            v2f   cc = w2p[0]*rs01.x + w2p[1]*rs01.y + w2p[2]*rs3;
            float c2 = w2r2[0]*rs01.x + w2r2[1]*rs01.y + w2r2[2]*rs3;
            float c0 = cc.x, c1 = cc.y;

            // 4-lane pre-reduce
            c0 += __shfl_xor(c0, 1, 64); c0 += __shfl_xor(c0, 2, 64);
            c1 += __shfl_xor(c1, 1, 64); c1 += __shfl_xor(c1, 2, 64);
            c2 += __shfl_xor(c2, 1, 64); c2 += __shfl_xor(c2, 2, 64);
            if (wrt) {
                float* pp = &part[tt*PSTRIDE + g3];
                pp[0]  = c0;
                pp[33] = c1;
                pp[66] = c2;
            }
        }
        __syncthreads();
        // finish: thread i<48 handles (tt=i/3, o=i%3); store coalesced
        if (tid < 48) {
            const int rtt = tid / 3, ro = tid - rtt*3;
            const float* pp = &part[rtt*PSTRIDE + ro*33];
            float s = 0.0f;
            #pragma unroll
            for (int gg = 0; gg < 32; ++gg) s += pp[gg];
            outb[tc*3 + tid] = s;
        }
        __syncthreads();
    }
}

extern "C" void kernel_launch(void* const* d_in, const int* in_sizes, int n_in,
                              void* d_out, int out_size, void* d_ws, size_t ws_size,
                              hipStream_t stream) {
    const float* x  = (const float*)d_in[0];
    const float* W1 = (const float*)d_in[1];
    const float* W2 = (const float*)d_in[2];
    float* out = (float*)d_out;
    prnn_kernel<<<4096, 128, 0, stream>>>(x, W1, W2, out);
}

// Round 4
// 465.494 us; speedup vs baseline: 2.1526x; 1.5706x over previous
//
#include <hip/hip_runtime.h>
#include <math.h>

#define S_LEN 512
#define TCHUNK 16

typedef float v2f __attribute__((ext_vector_type(2)));

__device__ __forceinline__ float fast_rcp(float x) { return __builtin_amdgcn_rcpf(x); }
__device__ __forceinline__ float fast_rsq(float x) { return __builtin_amdgcn_rsqf(x); }
__device__ __forceinline__ float exp2s(float x)    { return __builtin_amdgcn_exp2f(x); }
__device__ __forceinline__ v2f exp2v(v2f a) { return (v2f){exp2s(a.x), exp2s(a.y)}; }
__device__ __forceinline__ v2f rcpv(v2f a)  { return (v2f){fast_rcp(a.x), fast_rcp(a.y)}; }
__device__ __forceinline__ v2f rsqv(v2f a)  { return (v2f){fast_rsq(a.x), fast_rsq(a.y)}; }
__device__ __forceinline__ v2f maxv(v2f a, v2f b) { return __builtin_elementwise_max(a, b); }
__device__ __forceinline__ v2f minv(v2f a, v2f b) { return __builtin_elementwise_min(a, b); }

// One thread handles material points (lane, lane+64) as the two halves of
// packed-f32 (v_pk_*_f32) vectors. 64 threads = 1 wave per block, 1 block per
// batch element; 4096 blocks = exactly 16 workgroups/CU (LDS < 10 KB).
__global__ __launch_bounds__(64, 4) void prnn_kernel(
    const float* __restrict__ x,
    const float* __restrict__ W1,
    const float* __restrict__ W2,
    float* __restrict__ out)
{
    // Material constants (compile-time double, truncated to f32)
    const float TWO_MU  = (float)(2.0 * (3130.0 / 2.6));
    const float LAM     = (float)(3130.0 * 0.3 / (1.3 * 0.4));
    const float AH      = 64.8f;
    const float Cf      = 0.003407f;
    const float K2      = (float)(1.4426950408889634 / 0.003407);    // log2(e)/C
    const float RCP3MU  = (float)(1.0 / (3.0 * (3130.0 / 2.6)));
    const float L2B3MC  = 1.449272f;                                 // log2(B/(3*MU*C))
    const float LOG2E   = 1.4426950408889634f;
    const float LNI08   = 0.5545177f;                                // 0.8*ln(2): 0.8*lnz from log2z

    const int b    = blockIdx.x;
    const int lane = threadIdx.x;          // 0..63; points A=lane, B=lane+64

    // Packed weights: component .x -> point A, .y -> point B
    v2f w1[3][3], w2[3][3];
    #pragma unroll
    for (int j = 0; j < 3; ++j)
        #pragma unroll
        for (int f = 0; f < 3; ++f)
            w1[j][f] = (v2f){ W1[(lane*3 + j)*3 + f], W1[((lane+64)*3 + j)*3 + f] };
    #pragma unroll
    for (int o = 0; o < 3; ++o)
        #pragma unroll
        for (int j = 0; j < 3; ++j)
            w2[o][j] = (v2f){ W2[o*384 + lane*3 + j], W2[o*384 + (lane+64)*3 + j] };

    __shared__ float xs0[S_LEN], xs1[S_LEN], xs2[S_LEN];   // SoA strain history, 6 KB
    __shared__ float part[TCHUNK][3][17];                  // 3.3 KB partials

    const float* xb = x + (size_t)b * (S_LEN*3);
    for (int t = lane; t < S_LEN; t += 64) {
        xs0[t] = xb[t*3 + 0];
        xs1[t] = xb[t*3 + 1];
        xs2[t] = xb[t*3 + 2];
    }
    __syncthreads();

    v2f ep0 = (v2f){0.f,0.f}, ep1 = ep0, ep2 = ep0, ep3 = ep0, kap = ep0;
    float* outb = out + (size_t)b * (S_LEN*3);

    for (int tc = 0; tc < S_LEN; tc += TCHUNK) {
        #pragma unroll 1
        for (int tt = 0; tt < TCHUNK; ++tt) {
            const int t = tc + tt;
            const float x0 = xs0[t], x1 = xs1[t], x2 = xs2[t];  // wave-uniform broadcasts

            // fc1 (packed over the 2 points)
            v2f e0 = w1[0][0]*x0 + w1[0][1]*x1 + w1[0][2]*x2;
            v2f e1 = w1[1][0]*x0 + w1[1][1]*x1 + w1[1][2]*x2;
            v2f gg = w1[2][0]*x0 + w1[2][1]*x1 + w1[2][2]*x2;

            // elastic trial (tensorial Voigt-4: xx,yy,zz,xy)
            v2f ee0 = e0 - ep0;
            v2f ee1 = e1 - ep1;
            v2f ee2 = -ep2;
            v2f ee3 = 0.5f*gg - ep3;
            v2f lt  = LAM * (ee0 + ee1 + ee2);
            v2f s0  = TWO_MU*ee0 + lt;
            v2f s1  = TWO_MU*ee1 + lt;
            v2f s2  = TWO_MU*ee2 + lt;
            v2f s3  = TWO_MU*ee3;                       // deviatoric shear == s3
            v2f p   = (s0 + s1 + s2) * (1.0f/3.0f);
            v2f d0 = s0 - p, d1 = s1 - p, d2 = s2 - p;
            v2f ss = d0*d0 + d1*d1 + d2*d2 + 2.0f*(s3*s3);
            v2f dot15 = maxv(1.5f*ss, (v2f){1e-24f,1e-24f});
            v2f qi = rsqv(dot15);                       // 1/q
            v2f q  = dot15 * qi;

            // dg = max(0, u0 + C*W(z)): exact root of the return map.
            // (f>0 <=> root>0, so no explicit yield check needed.)
            v2f u0  = (q - AH) * RCP3MU;
            v2f l2z = minv(L2B3MC - (kap + u0)*K2, (v2f){30.f,30.f});
            v2f z   = exp2v(l2z);
            v2f w   = maxv(LNI08*l2z, z*rcpv(1.0f + z));   // init
            // one Halley step (cubic): F = w e^w - z
            v2f y    = exp2v(w * LOG2E);
            v2f F    = w*y - z;
            v2f Fp   = w*y + y;
            v2f w2a  = 2.0f + w;
            v2f h    = F*y;
            v2f den  = Fp*Fp - 0.5f*(h*w2a);
            w = w - (F*Fp)*rcpv(den);
            v2f dg = maxv(u0 + Cf*w, (v2f){0.f,0.f});

            // radial return + state update (exact no-op where dg==0)
            v2f c  = 1.5f*dg*qi;
            v2f t2 = TWO_MU*c;
            v2f r0 = s0 - t2*d0;
            v2f r1 = s1 - t2*d1;
            v2f r3 = s3 - t2*s3;
            ep0 += c*d0; ep1 += c*d1; ep2 += c*d2; ep3 += c*s3;
            kap += dg;

            // fc2: pair-sum then cross-lane reduce
            v2f a0 = w2[0][0]*r0 + w2[0][1]*r1 + w2[0][2]*r3;
            v2f a1 = w2[1][0]*r0 + w2[1][1]*r1 + w2[1][2]*r3;
            v2f a2 = w2[2][0]*r0 + w2[2][1]*r1 + w2[2][2]*r3;
            float c0 = a0.x + a0.y;
            float c1 = a1.x + a1.y;
            float c2 = a2.x + a2.y;

            // 4-lane pre-reduce
            c0 += __shfl_xor(c0, 1, 64); c0 += __shfl_xor(c0, 2, 64);
            c1 += __shfl_xor(c1, 1, 64); c1 += __shfl_xor(c1, 2, 64);
            c2 += __shfl_xor(c2, 1, 64); c2 += __shfl_xor(c2, 2, 64);
            if ((lane & 3) == 0) {
                const int g = lane >> 2;       // 0..15
                part[tt][0][g] = c0;
                part[tt][1][g] = c1;
                part[tt][2][g] = c2;
            }
        }
        __syncthreads();
        // finish: lane r<48 handles (tt=r/3, o=r%3); 16 adds; coalesced store
        if (lane < 48) {
            const int rtt = lane / 3, ro = lane - rtt*3;
            float s = 0.0f;
            #pragma unroll
            for (int g = 0; g < 16; ++g) s += part[rtt][ro][g];
            outb[tc*3 + lane] = s;
        }
        __syncthreads();
    }
}

extern "C" void kernel_launch(void* const* d_in, const int* in_sizes, int n_in,
                              void* d_out, int out_size, void* d_ws, size_t ws_size,
                              hipStream_t stream) {
    const float* x  = (const float*)d_in[0];
    const float* W1 = (const float*)d_in[1];
    const float* W2 = (const float*)d_in[2];
    float* out = (float*)d_out;
    prnn_kernel<<<4096, 64, 0, stream>>>(x, W1, W2, out);
}

// Round 5
// 421.364 us; speedup vs baseline: 2.3780x; 1.1047x over previous
//
#include <hip/hip_runtime.h>
#include <math.h>

#define S_LEN 512
#define TCHUNK 16

typedef float v2f __attribute__((ext_vector_type(2)));

__device__ __forceinline__ float fast_rcp(float x) { return __builtin_amdgcn_rcpf(x); }
__device__ __forceinline__ float fast_rsq(float x) { return __builtin_amdgcn_rsqf(x); }
__device__ __forceinline__ float exp2s(float x)    { return __builtin_amdgcn_exp2f(x); }
__device__ __forceinline__ v2f exp2v(v2f a) { return (v2f){exp2s(a.x), exp2s(a.y)}; }
__device__ __forceinline__ v2f rcpv(v2f a)  { return (v2f){fast_rcp(a.x), fast_rcp(a.y)}; }
__device__ __forceinline__ v2f rsqv(v2f a)  { return (v2f){fast_rsq(a.x), fast_rsq(a.y)}; }
__device__ __forceinline__ v2f maxv(v2f a, v2f b) { return __builtin_elementwise_max(a, b); }

// 2 waves/block; each wave owns one batch element; each thread owns material
// points (lane, lane+64) packed as v2f. 2048 blocks -> 8 blocks/CU (LDS 18.4KB)
// -> 16 waves/CU.
__global__ __launch_bounds__(128, 4) void prnn_kernel(
    const float* __restrict__ x,
    const float* __restrict__ W1,
    const float* __restrict__ W2,
    float* __restrict__ out)
{
    // Material constants (compile-time double, truncated to f32)
    const float MU      = (float)(3130.0 / 2.6);
    const float THREE_MU= (float)(3.0 * (3130.0 / 2.6));
    const float C43     = (float)(4.0 * (3130.0 / 2.6) / 3.0);   // 4mu/3
    const float C23     = (float)(2.0 * (3130.0 / 2.6) / 3.0);   // 2mu/3
    const float CP      = (float)(7825.0 / 3.0);                 // (E/(1-2nu))/3
    const float AH      = 64.8f;
    const float Cf      = 0.003407f;
    const float K2      = (float)(1.4426950408889634 / 0.003407);  // log2(e)/C
    const float R3M     = (float)(1.0 / (3.0 * (3130.0 / 2.6)));   // 1/(3mu)
    const float AR3M    = (float)(64.8 / (3.0 * (3130.0 / 2.6)));  // A/(3mu)
    const float L2B3MC  = 1.449290f;                               // log2(B/(3muC))
    const float LOG2E   = 1.4426950408889634f;
    const float LNI08   = (float)(0.8 * 0.6931471805599453);       // 0.8*ln2

    const int lane = threadIdx.x & 63;
    const int wv   = threadIdx.x >> 6;
    const int b    = blockIdx.x * 2 + wv;

    // Load fc1 rows a,b,c for both points, fold into deviatoric map + pressure row.
    v2f D0[3], D1[3], D3[3], pv[3];
    #pragma unroll
    for (int f = 0; f < 3; ++f) {
        const int mA = lane, mB = lane + 64;
        v2f av = (v2f){ W1[(mA*3 + 0)*3 + f], W1[(mB*3 + 0)*3 + f] };
        v2f bv = (v2f){ W1[(mA*3 + 1)*3 + f], W1[(mB*3 + 1)*3 + f] };
        v2f cv = (v2f){ W1[(mA*3 + 2)*3 + f], W1[(mB*3 + 2)*3 + f] };
        D0[f] = C43*av - C23*bv;
        D1[f] = C43*bv - C23*av;
        D3[f] = MU*cv;
        pv[f] = CP*(av + bv);
    }
    v2f w2[3][3];
    #pragma unroll
    for (int o = 0; o < 3; ++o)
        #pragma unroll
        for (int j = 0; j < 3; ++j)
            w2[o][j] = (v2f){ W2[o*384 + lane*3 + j], W2[o*384 + (lane+64)*3 + j] };

    __shared__ float xs[2][S_LEN*3];              // 12 KB
    __shared__ float part[2][TCHUNK][3][17];      // 6.4 KB

    const float* xb = x + (size_t)b * (S_LEN*3);
    for (int i = lane; i < S_LEN*3; i += 64) xs[wv][i] = xb[i];
    __syncthreads();

    // State: deviatoric plastic stress sp = 2mu*ep (3 live comps), kappa.
    v2f sp0 = (v2f){0.f,0.f}, sp1 = sp0, sp3 = sp0, kap = sp0;
    float* outb = out + (size_t)b * (S_LEN*3);

    for (int tc = 0; tc < S_LEN; tc += TCHUNK) {
        #pragma unroll 1
        for (int tt = 0; tt < TCHUNK; ++tt) {
            const int t = tc + tt;
            const float x0 = xs[wv][t*3+0], x1 = xs[wv][t*3+1], x2 = xs[wv][t*3+2];

            // trial deviatoric stress (x-part) + pressure, via precomputed maps
            v2f d0 = D0[0]*x0 + D0[1]*x1 + D0[2]*x2 - sp0;
            v2f d1 = D1[0]*x0 + D1[1]*x1 + D1[2]*x2 - sp1;
            v2f d3 = D3[0]*x0 + D3[1]*x1 + D3[2]*x2 - sp3;
            v2f p  = pv[0]*x0 + pv[1]*x1 + pv[2]*x2;

            // q^2 = 3(d0^2 + d1^2 + d0 d1 + d3^2)   [d2 = -(d0+d1)]
            v2f h   = d0*d0 + d1*d1 + d0*d1 + d3*d3;
            v2f dot = maxv(3.0f*h, (v2f){1e-24f,1e-24f});
            v2f qi  = rsqv(dot);                  // 1/q
            v2f q   = dot * qi;

            // dg = max(0, u0 + C*W(z)) — exact root of the return map
            v2f u0  = q*R3M - AR3M;
            v2f l2z = L2B3MC - (kap + u0)*K2;
            v2f z   = exp2v(l2z);
            v2f w   = maxv(LNI08*l2z, z*rcpv(1.0f + z));   // init (err <= ~0.2)
            // one Halley step on F = w e^w - z (cubic)
            v2f y   = exp2v(w * LOG2E);
            v2f F   = w*y - z;
            v2f Fp  = w*y + y;
            v2f den = Fp*Fp + (F*y)*(-1.0f - 0.5f*w);
            w = w - (F*Fp)*rcpv(den);
            v2f dg  = maxv(u0 + Cf*w, (v2f){0.f,0.f});

            // radial return in stress space (exact no-op where dg==0)
            v2f t2 = THREE_MU*dg*qi;
            v2f u  = 1.0f - t2;
            sp0 += t2*d0; sp1 += t2*d1; sp3 += t2*d3;
            kap += dg;
            v2f r0 = u*d0 + p;
            v2f r1 = u*d1 + p;
            v2f r3 = u*d3;

            // fc2 contribution, pair-sum, 4-lane pre-reduce
            v2f a0 = w2[0][0]*r0 + w2[0][1]*r1 + w2[0][2]*r3;
            v2f a1 = w2[1][0]*r0 + w2[1][1]*r1 + w2[1][2]*r3;
            v2f a2 = w2[2][0]*r0 + w2[2][1]*r1 + w2[2][2]*r3;
            float c0 = a0.x + a0.y;
            float c1 = a1.x + a1.y;
            float c2 = a2.x + a2.y;
            c0 += __shfl_xor(c0, 1, 64); c0 += __shfl_xor(c0, 2, 64);
            c1 += __shfl_xor(c1, 1, 64); c1 += __shfl_xor(c1, 2, 64);
            c2 += __shfl_xor(c2, 1, 64); c2 += __shfl_xor(c2, 2, 64);
            if ((lane & 3) == 0) {
                const int g = lane >> 2;
                part[wv][tt][0][g] = c0;
                part[wv][tt][1][g] = c1;
                part[wv][tt][2][g] = c2;
            }
        }
        __syncthreads();
        if (lane < 48) {
            const int rtt = lane / 3, ro = lane - rtt*3;
            float s = 0.0f;
            #pragma unroll
            for (int g = 0; g < 16; ++g) s += part[wv][rtt][ro][g];
            outb[tc*3 + lane] = s;
        }
        __syncthreads();
    }
}

extern "C" void kernel_launch(void* const* d_in, const int* in_sizes, int n_in,
                              void* d_out, int out_size, void* d_ws, size_t ws_size,
                              hipStream_t stream) {
    const float* x  = (const float*)d_in[0];
    const float* W1 = (const float*)d_in[1];
    const float* W2 = (const float*)d_in[2];
    float* out = (float*)d_out;
    prnn_kernel<<<2048, 128, 0, stream>>>(x, W1, W2, out);
}